// Round 3
// baseline (20849.934 us; speedup 1.0000x reference)
//
#include <hip/hip_runtime.h>
#include <hip/hip_bf16.h>

#define Bb 256
#define Tt 512
#define Ff 256
#define Hh 1024
#define Cc 128
#define NBLK 256
#define NTHR 512

typedef __bf16 bf16;
typedef bf16 bf16x8 __attribute__((ext_vector_type(8)));
typedef float f32x4 __attribute__((ext_vector_type(4)));

#define MFMA(a, b, c) __builtin_amdgcn_mfma_f32_16x16x32_bf16(a, b, c, 0, 0, 0)

struct SMem {
    bf16x8 w[2 * 64 * 64];      // MFMA A-frag order [(mt*KI+ki)*64+lane]; L2 blocks use all 128 KB
    float scratch[32 * 129];    // gate scratch, padded stride 129
    float bias[32];
    bf16 hstage[8 * 256];       // [hu][b] staging for coalesced h writeback
};

__device__ __forceinline__ float fsig(float x) {
    x = fminf(30.f, fmaxf(-30.f, x));
    return __builtin_amdgcn_rcpf(1.f + __expf(-x));
}
__device__ __forceinline__ float ftanh(float x) {
    x = fminf(15.f, fmaxf(-15.f, x));
    float e = __expf(2.f * x);
    return (e - 1.f) * __builtin_amdgcn_rcpf(e + 1.f);
}

// sc1: device-coherent (MALL) path — producers/consumers across XCDs
#define LDX4_SC1(dst, base) \
    asm volatile("global_load_dwordx4 %0, %1, off sc1" : "=v"(dst) : "v"(base) : "memory")
#define STX4_SC1(p, v) \
    asm volatile("global_store_dwordx4 %0, %1, off sc1" :: "v"(p), "v"(v) : "memory")
// sc0: L1-bypass, local-L2 hit — intra-XCD coherent reads of the staging buffer
#define LDX4_SC0(dst, base, OFF) \
    asm volatile("global_load_dwordx4 %0, %1, off offset:" #OFF " sc0" : "=v"(dst) : "v"(base))

// issue 16 staging loads (one 8-iter chunk: 8 from P0, 8 from P1)
#define ISSUE_CHUNK(B0, B1, P0, P1) do { \
    LDX4_SC0(B0[0], (P0), 0);   LDX4_SC0(B0[1], (P0), 64);  LDX4_SC0(B0[2], (P0), 128); LDX4_SC0(B0[3], (P0), 192); \
    LDX4_SC0(B0[4], (P0), 256); LDX4_SC0(B0[5], (P0), 320); LDX4_SC0(B0[6], (P0), 384); LDX4_SC0(B0[7], (P0), 448); \
    LDX4_SC0(B1[0], (P1), 0);   LDX4_SC0(B1[1], (P1), 64);  LDX4_SC0(B1[2], (P1), 128); LDX4_SC0(B1[3], (P1), 192); \
    LDX4_SC0(B1[4], (P1), 256); LDX4_SC0(B1[5], (P1), 320); LDX4_SC0(B1[6], (P1), 384); LDX4_SC0(B1[7], (P1), 448); \
} while (0)

#define WAITV(N, B0, B1) \
    asm volatile("s_waitcnt vmcnt(" #N ")" : \
        "+v"(B0[0]), "+v"(B0[1]), "+v"(B0[2]), "+v"(B0[3]), \
        "+v"(B0[4]), "+v"(B0[5]), "+v"(B0[6]), "+v"(B0[7]), \
        "+v"(B1[0]), "+v"(B1[1]), "+v"(B1[2]), "+v"(B1[3]), \
        "+v"(B1[4]), "+v"(B1[5]), "+v"(B1[6]), "+v"(B1[7]) :: "memory")

#define MFMA8(ABASE, B0, B1) do { \
    _Pragma("unroll") \
    for (int _i = 0; _i < 8; ++_i) { \
        bf16x8 _a0 = wA0[((ABASE) + _i) * 64 + lane]; \
        bf16x8 _a1 = wA1[((ABASE) + _i) * 64 + lane]; \
        bf16x8 _b0 = __builtin_bit_cast(bf16x8, B0[_i]); \
        bf16x8 _b1 = __builtin_bit_cast(bf16x8, B1[_i]); \
        acc00 = MFMA(_a0, _b0, acc00); acc10 = MFMA(_a1, _b0, acc10); \
        acc01 = MFMA(_a0, _b1, acc01); acc11 = MFMA(_a1, _b1, acc11); \
    } \
} while (0)

// 32 k-iters (K=1024) from XCD-local staging, 2-chunk-deep load pipeline
__device__ __forceinline__ void mm32(const bf16x8* __restrict__ wA0, const bf16x8* __restrict__ wA1,
                                     int abase, const bf16* p0, const bf16* p1, int lane,
                                     f32x4& acc00, f32x4& acc01, f32x4& acc10, f32x4& acc11)
{
    f32x4 bx0[8], bx1[8], by0[8], by1[8];
    asm volatile("s_waitcnt vmcnt(0)" ::: "memory");   // exact-count precondition
    ISSUE_CHUNK(bx0, bx1, p0, p1);
    ISSUE_CHUNK(by0, by1, p0 + 256, p1 + 256);
    WAITV(16, bx0, bx1);
    MFMA8(abase + 0, bx0, bx1);
    ISSUE_CHUNK(bx0, bx1, p0 + 512, p1 + 512);
    WAITV(16, by0, by1);
    MFMA8(abase + 8, by0, by1);
    ISSUE_CHUNK(by0, by1, p0 + 768, p1 + 768);
    WAITV(16, bx0, bx1);
    MFMA8(abase + 16, bx0, bx1);
    WAITV(0, by0, by1);
    MFMA8(abase + 24, by0, by1);
}

// distributed-flag grid barrier (through MALL)
__device__ __forceinline__ void grid_barrier2(unsigned* arrive, unsigned target, int tid, int bid) {
    __syncthreads();   // per-wave vmcnt drain before s_barrier -> sc1 h-stores device-visible
    if (tid == 0)
        __hip_atomic_store(&arrive[bid], target, __ATOMIC_RELAXED, __HIP_MEMORY_SCOPE_AGENT);
    if (tid < 64) {
        for (;;) {
            int ok = 1;
            #pragma unroll
            for (int j = 0; j < 4; ++j) {
                unsigned v = __hip_atomic_load(&arrive[tid * 4 + j], __ATOMIC_RELAXED,
                                               __HIP_MEMORY_SCOPE_AGENT);
                ok &= (v >= target);
            }
            if (__all(ok)) break;
            __builtin_amdgcn_s_sleep(2);
        }
    }
    __syncthreads();
}

// per-XCD barrier between copy-in and compute (flags through MALL; only 'total' arrivals)
__device__ __forceinline__ void xcd_barrier(unsigned* xflags, int xcc, int rank, int total,
                                            unsigned tgt, int tid) {
    __syncthreads();   // drain this block's staging stores to local L2
    if (tid == 0)
        __hip_atomic_store(&xflags[xcc * 256 + rank], tgt, __ATOMIC_RELAXED, __HIP_MEMORY_SCOPE_AGENT);
    if (tid < 64) {
        for (;;) {
            int ok = 1;
            for (int j = tid; j < 256; j += 64) {
                if (j < total) {
                    unsigned v = __hip_atomic_load(&xflags[xcc * 256 + j], __ATOMIC_RELAXED,
                                                   __HIP_MEMORY_SCOPE_AGENT);
                    ok &= (v >= tgt);
                }
            }
            if (__all(ok)) break;
            __builtin_amdgcn_s_sleep(1);
        }
    }
    __syncthreads();
}

__device__ __forceinline__ void epilogue(SMem& sm, f32x4 acc00, f32x4 acc01, f32x4 acc10, f32x4 acc11,
                                         float creg[4], bf16* hdst, int hu0, bool extra_tanh) {
    const int tid = threadIdx.x;
    const int lane = tid & 63, wv = tid >> 6, quad = lane >> 4, l15 = lane & 15;
    const int colb = (wv & 3) * 32;
    #pragma unroll
    for (int ph = 0; ph < 2; ++ph) {
        if ((wv >> 2) == ph) {
            #pragma unroll
            for (int r = 0; r < 4; ++r) {
                sm.scratch[(quad * 4 + r) * 129 + colb + l15]           = acc00[r];
                sm.scratch[(quad * 4 + r) * 129 + colb + 16 + l15]      = acc01[r];
                sm.scratch[(16 + quad * 4 + r) * 129 + colb + l15]      = acc10[r];
                sm.scratch[(16 + quad * 4 + r) * 129 + colb + 16 + l15] = acc11[r];
            }
        }
        __syncthreads();
        #pragma unroll
        for (int pi = 0; pi < 2; ++pi) {
            int idx = pi * NTHR + tid;      // 0..1023
            int bl = idx & 127, hu = idx >> 7;
            float gi = sm.scratch[hu * 129 + bl]        + sm.bias[hu];
            float gf = sm.scratch[(8 + hu) * 129 + bl]  + sm.bias[8 + hu];
            float gg = sm.scratch[(16 + hu) * 129 + bl] + sm.bias[16 + hu];
            float go = sm.scratch[(24 + hu) * 129 + bl] + sm.bias[24 + hu];
            float iv = fsig(gi), fv = fsig(gf), gv = ftanh(gg), ov = fsig(go);
            float c = fv * creg[ph * 2 + pi] + iv * gv;
            creg[ph * 2 + pi] = c;
            float h = ov * ftanh(c);
            if (extra_tanh) h = ftanh(h);   // layer-2 recurrent state is tanh'd
            sm.hstage[hu * 256 + (bl + 128 * ph)] = (bf16)h;
        }
        __syncthreads();
    }
    if (tid < 256) {
        bf16x8 v;
        #pragma unroll
        for (int e = 0; e < 8; ++e) v[e] = sm.hstage[e * 256 + tid];
        bf16* p = hdst + (size_t)tid * Hh + hu0;
        f32x4 pv = __builtin_bit_cast(f32x4, v);
        STX4_SC1(p, pv);                    // write-through to MALL for next stage's copy-in
    }
}

__global__ void __launch_bounds__(NTHR, 2)
lstm_kernel(const float* __restrict__ y,
            const float* __restrict__ Wih1, const float* __restrict__ Whh1,
            const float* __restrict__ bih1, const float* __restrict__ bhh1,
            const float* __restrict__ Wih2, const float* __restrict__ Whh2,
            const float* __restrict__ bih2, const float* __restrict__ bhh2,
            const float* __restrict__ Wout, const float* __restrict__ bout,
            float* __restrict__ out,
            bf16* __restrict__ h1b0, bf16* __restrict__ h1b1,
            bf16* __restrict__ h2b0, bf16* __restrict__ h2b1,
            unsigned* __restrict__ arrive, unsigned* __restrict__ regcnt,
            unsigned* __restrict__ xflags, bf16* __restrict__ stg)
{
    __shared__ SMem sm;
    __shared__ int sh_rank, sh_total;
    const int tid = threadIdx.x;
    const int bid = blockIdx.x;
    const bool isL2 = bid >= 128;
    const int hu0 = (bid & 127) * 8;
    const int KI = isL2 ? 64 : 40;      // k-iters: L1 K=1280 (8 x + 32 h), L2 K=2048
    const int lane = tid & 63;
    const int wv = tid >> 6;
    const int quad = lane >> 4;
    const int l15 = lane & 15;

    // ---- XCD identity + per-XCD rank registration ----
    int xcc;
    asm("s_getreg_b32 %0, hwreg(HW_REG_XCC_ID)" : "=s"(xcc));
    xcc &= 7;
    if (tid == 0)
        sh_rank = (int)__hip_atomic_fetch_add(&regcnt[xcc], 1u, __ATOMIC_RELAXED,
                                              __HIP_MEMORY_SCOPE_AGENT);
    bf16* st1 = stg + (size_t)xcc * (2 * Bb * Hh);   // XCD-local h1[s-1] copy (512 KB)
    bf16* st2 = st1 + Bb * Hh;                       // XCD-local h2[s-2] copy (512 KB)

    // ---- one-time init: bias + pack weights into LDS in MFMA A-frag order ----
    if (tid < 32) {
        int gate = tid >> 3, j = tid & 7;
        int grow = gate * Hh + hu0 + j;
        sm.bias[tid] = isL2 ? (bih2[grow] + bhh2[grow]) : (bih1[grow] + bhh1[grow]);
    }
    for (int slot = tid; slot < 2 * KI * 64; slot += NTHR) {
        int mt = slot / (KI * 64);
        int ki = (slot / 64) % KI;
        int ln = slot & 63;
        int row = mt * 16 + (ln & 15);
        int k = ki * 32 + (ln >> 4) * 8;
        int gate = row >> 3, j = row & 7;
        int grow = gate * Hh + hu0 + j;
        const float* src;
        if (!isL2) src = (k < Ff) ? (Wih1 + (size_t)grow * Ff + k) : (Whh1 + (size_t)grow * Hh + (k - Ff));
        else       src = (k < Hh) ? (Wih2 + (size_t)grow * Hh + k) : (Whh2 + (size_t)grow * Hh + (k - Hh));
        bf16x8 fr;
        #pragma unroll
        for (int e = 0; e < 8; ++e) fr[e] = (bf16)src[e];
        sm.w[slot] = fr;
    }
    float creg[4] = {0.f, 0.f, 0.f, 0.f};
    __syncthreads();

    // all registrations complete after this barrier; then read per-XCD block count
    grid_barrier2(arrive, 1u, tid, bid);
    if (tid == 0)
        sh_total = (int)__hip_atomic_load(&regcnt[xcc], __ATOMIC_RELAXED, __HIP_MEMORY_SCOPE_AGENT);
    __syncthreads();
    const int rank = sh_rank, total = sh_total;

    const int nb0 = wv * 32 + l15;      // batch row for nt=0 (nt=1 is +16)
    const bf16x8* wA0 = sm.w;
    const bf16x8* wA1 = sm.w + KI * 64;

    // ---- pipelined stages: stage s runs L1(t=s) and L2(t=s-1) ----
    for (int s = 0; s <= Tt; ++s) {
        // -- copy-in: this XCD's private copy of h1[s-1], h2[s-2] (stage-(s-1) products) --
        {
            const int gtid = rank * NTHR + tid;
            const int stride = total * NTHR;
            if (s >= 1) {
                const f32x4* src = (const f32x4*)(((s - 1) & 1) ? h1b1 : h1b0);
                f32x4* dst = (f32x4*)st1;
                for (int c = gtid; c < (Bb * Hh * 2) / 16; c += stride) {
                    f32x4 v; LDX4_SC1(v, src + c);
                    asm volatile("s_waitcnt vmcnt(0)" ::: "memory");
                    dst[c] = v;                     // plain store -> lands dirty in local L2
                }
            }
            if (s >= 2) {
                const f32x4* src = (const f32x4*)(((s - 2) & 1) ? h2b1 : h2b0);
                f32x4* dst = (f32x4*)st2;
                for (int c = gtid; c < (Bb * Hh * 2) / 16; c += stride) {
                    f32x4 v; LDX4_SC1(v, src + c);
                    asm volatile("s_waitcnt vmcnt(0)" ::: "memory");
                    dst[c] = v;
                }
            }
        }
        xcd_barrier(xflags, xcc, rank, total, (unsigned)(s + 1), tid);

        bool active = isL2 ? (s >= 1) : (s < Tt);
        if (active) {
            const int t = isL2 ? (s - 1) : s;
            f32x4 acc00 = {0,0,0,0}, acc01 = {0,0,0,0}, acc10 = {0,0,0,0}, acc11 = {0,0,0,0};
            if (!isL2) {
                // x-part: K [0,256) from y (read-only, plain cached loads)
                const f32x4* x0v = (const f32x4*)(y + ((size_t)nb0 * Tt + t) * Ff) + quad * 2;
                const f32x4* x1v = x0v + (size_t)16 * Tt * (Ff / 4);
                #pragma unroll
                for (int ki = 0; ki < 8; ++ki) {
                    bf16x8 a0 = wA0[ki * 64 + lane];
                    bf16x8 a1 = wA1[ki * 64 + lane];
                    f32x4 u0 = x0v[ki * 8], u1 = x0v[ki * 8 + 1];
                    f32x4 w0 = x1v[ki * 8], w1 = x1v[ki * 8 + 1];
                    bf16x8 b0, b1;
                    #pragma unroll
                    for (int e = 0; e < 4; ++e) {
                        b0[e] = (bf16)u0[e]; b0[4 + e] = (bf16)u1[e];
                        b1[e] = (bf16)w0[e]; b1[4 + e] = (bf16)w1[e];
                    }
                    acc00 = MFMA(a0, b0, acc00); acc10 = MFMA(a1, b0, acc10);
                    acc01 = MFMA(a0, b1, acc01); acc11 = MFMA(a1, b1, acc11);
                }
                if (t > 0) {    // h-part: K [256,1280) from XCD-local h1[s-1]
                    const bf16* p0 = st1 + (size_t)nb0 * Hh + quad * 8;
                    mm32(wA0, wA1, 8, p0, p0 + 16 * Hh, lane, acc00, acc01, acc10, acc11);
                }
                epilogue(sm, acc00, acc01, acc10, acc11, creg, (t & 1) ? h1b1 : h1b0, hu0, false);
            } else {
                // h1-part: K [0,1024) from XCD-local h1[t]=h1[s-1]
                const bf16* p0 = st1 + (size_t)nb0 * Hh + quad * 8;
                mm32(wA0, wA1, 0, p0, p0 + 16 * Hh, lane, acc00, acc01, acc10, acc11);
                if (t > 0) {    // h2-part: K [1024,2048) from XCD-local h2[t-1]=h2[s-2]
                    const bf16* q0 = st2 + (size_t)nb0 * Hh + quad * 8;
                    mm32(wA0, wA1, 32, q0, q0 + 16 * Hh, lane, acc00, acc01, acc10, acc11);
                }
                epilogue(sm, acc00, acc01, acc10, acc11, creg, (t & 1) ? h2b1 : h2b0, hu0, true);
            }
        }
        grid_barrier2(arrive, (unsigned)(s + 2), tid, bid);
    }

    // ---- final: out = relu(h2[511] @ Wout^T + bout); h2[511] in h2b1 (MALL via sc1) ----
    if (bid < 16) {
        const int bb = bid * 16 + l15;
        const float* ap = Wout + (size_t)(wv * 16 + l15) * Hh + quad * 8;
        const bf16* bp = h2b1 + (size_t)bb * Hh + quad * 8;
        f32x4 acc = {0,0,0,0};
        for (int ki = 0; ki < 32; ++ki) {
            bf16x8 a;
            #pragma unroll
            for (int e = 0; e < 8; ++e) a[e] = (bf16)ap[ki * 32 + e];
            f32x4 braw;
            LDX4_SC1(braw, (const f32x4*)(bp + ki * 32));
            asm volatile("s_waitcnt vmcnt(0)" ::: "memory");
            bf16x8 b = __builtin_bit_cast(bf16x8, braw);
            acc = MFMA(a, b, acc);
        }
        #pragma unroll
        for (int r = 0; r < 4; ++r) {
            int orow = wv * 16 + quad * 4 + r;
            float v = acc[r] + bout[orow];
            out[(size_t)bb * Cc + orow] = fmaxf(v, 0.f);
        }
    }
}

extern "C" void kernel_launch(void* const* d_in, const int* in_sizes, int n_in,
                              void* d_out, int out_size, void* d_ws, size_t ws_size,
                              hipStream_t stream) {
    const float* y    = (const float*)d_in[0];
    const float* Wih1 = (const float*)d_in[1];
    const float* Whh1 = (const float*)d_in[2];
    const float* bih1 = (const float*)d_in[3];
    const float* bhh1 = (const float*)d_in[4];
    const float* Wih2 = (const float*)d_in[5];
    const float* Whh2 = (const float*)d_in[6];
    const float* bih2 = (const float*)d_in[7];
    const float* bhh2 = (const float*)d_in[8];
    const float* Wout = (const float*)d_in[9];
    const float* bout = (const float*)d_in[10];
    float* out = (float*)d_out;

    char* ws = (char*)d_ws;
    unsigned* arrive = (unsigned*)ws;               // 256 flags @ 0
    unsigned* regcnt = (unsigned*)(ws + 1024);      // 8 counters
    unsigned* xflags = (unsigned*)(ws + 2048);      // 8*256 flags (8 KB)
    bf16* h1b0 = (bf16*)(ws + 16384);
    bf16* h1b1 = (bf16*)(ws + 16384 + 1 * 524288);
    bf16* h2b0 = (bf16*)(ws + 16384 + 2 * 524288);
    bf16* h2b1 = (bf16*)(ws + 16384 + 3 * 524288);
    bf16* stg  = (bf16*)(ws + 16384 + 4 * 524288);  // 8 XCDs x 1 MB staging

    hipMemsetAsync(ws, 0, 16384, stream);           // zero all control flags/counters

    void* args[] = { &y, &Wih1, &Whh1, &bih1, &bhh1, &Wih2, &Whh2, &bih2, &bhh2,
                     &Wout, &bout, &out, &h1b0, &h1b1, &h2b0, &h2b1,
                     &arrive, &regcnt, &xflags, &stg };
    hipLaunchCooperativeKernel((void*)lstm_kernel, dim3(NBLK), dim3(NTHR), args, 0, stream);
}

// Round 5
// 20488.861 us; speedup vs baseline: 1.0176x; 1.0176x over previous
//
#include <hip/hip_runtime.h>
#include <hip/hip_bf16.h>

#define Bb 256
#define Tt 512
#define Ff 256
#define Hh 1024
#define Cc 128
#define NBLK 256
#define NTHR 512

typedef __bf16 bf16;
typedef bf16 bf16x8 __attribute__((ext_vector_type(8)));
typedef float f32x4 __attribute__((ext_vector_type(4)));

#define MFMA(a, b, c) __builtin_amdgcn_mfma_f32_16x16x32_bf16(a, b, c, 0, 0, 0)

struct SMem {
    bf16x8 w[2 * 64 * 64];      // MFMA A-frag order; L2 blocks use all 128 KB
    float scratch[32 * 129];    // gate scratch, padded stride 129
    float bias[32];
    bf16 hstage[8 * 256];       // [hu][b] staging for coalesced h writeback
};

__device__ __forceinline__ float fsig(float x) {
    x = fminf(30.f, fmaxf(-30.f, x));
    return __builtin_amdgcn_rcpf(1.f + __expf(-x));
}
__device__ __forceinline__ float ftanh(float x) {
    x = fminf(15.f, fmaxf(-15.f, x));
    float e = __expf(2.f * x);
    return (e - 1.f) * __builtin_amdgcn_rcpf(e + 1.f);
}

// sc1: device-coherent (MALL) path — cross-XCD producer/consumer (R2-proven)
#define LDX4_SC1(dst, base) \
    asm volatile("global_load_dwordx4 %0, %1, off sc1" : "=v"(dst) : "v"(base) : "memory")
#define STX4_SC1(p, v) \
    asm volatile("global_store_dwordx4 %0, %1, off sc1" :: "v"(p), "v"(v) : "memory")
// plain cached load (L1+L2) — used ONLY on XCD-local staging after buffer_inv
#define LDX4_PLAIN(dst, base, OFF) \
    asm volatile("global_load_dwordx4 %0, %1, off offset:" #OFF : "=v"(dst) : "v"(base))

// vector-L1 flash invalidate (no sc1 -> L2 untouched)
#define L1_INV() asm volatile("buffer_inv" ::: "memory")

#define ISSUE_CHUNK(B0, B1, P0, P1) do { \
    LDX4_PLAIN(B0[0], (P0), 0);   LDX4_PLAIN(B0[1], (P0), 64);  LDX4_PLAIN(B0[2], (P0), 128); LDX4_PLAIN(B0[3], (P0), 192); \
    LDX4_PLAIN(B0[4], (P0), 256); LDX4_PLAIN(B0[5], (P0), 320); LDX4_PLAIN(B0[6], (P0), 384); LDX4_PLAIN(B0[7], (P0), 448); \
    LDX4_PLAIN(B1[0], (P1), 0);   LDX4_PLAIN(B1[1], (P1), 64);  LDX4_PLAIN(B1[2], (P1), 128); LDX4_PLAIN(B1[3], (P1), 192); \
    LDX4_PLAIN(B1[4], (P1), 256); LDX4_PLAIN(B1[5], (P1), 320); LDX4_PLAIN(B1[6], (P1), 384); LDX4_PLAIN(B1[7], (P1), 448); \
} while (0)

#define WAITV(N, B0, B1) \
    asm volatile("s_waitcnt vmcnt(" #N ")" : \
        "+v"(B0[0]), "+v"(B0[1]), "+v"(B0[2]), "+v"(B0[3]), \
        "+v"(B0[4]), "+v"(B0[5]), "+v"(B0[6]), "+v"(B0[7]), \
        "+v"(B1[0]), "+v"(B1[1]), "+v"(B1[2]), "+v"(B1[3]), \
        "+v"(B1[4]), "+v"(B1[5]), "+v"(B1[6]), "+v"(B1[7]) :: "memory")

#define MFMA8(ABASE, B0, B1) do { \
    _Pragma("unroll") \
    for (int _i = 0; _i < 8; ++_i) { \
        bf16x8 _a0 = wA0[((ABASE) + _i) * 64 + lane]; \
        bf16x8 _a1 = wA1[((ABASE) + _i) * 64 + lane]; \
        bf16x8 _b0 = __builtin_bit_cast(bf16x8, B0[_i]); \
        bf16x8 _b1 = __builtin_bit_cast(bf16x8, B1[_i]); \
        acc00 = MFMA(_a0, _b0, acc00); acc10 = MFMA(_a1, _b0, acc10); \
        acc01 = MFMA(_a0, _b1, acc01); acc11 = MFMA(_a1, _b1, acc11); \
    } \
} while (0)

// 32 k-iters (K=1024) from XCD-local staging via cached loads, 2-chunk pipeline
__device__ __forceinline__ void mm32(const bf16x8* __restrict__ wA0, const bf16x8* __restrict__ wA1,
                                     int abase, const bf16* p0, const bf16* p1, int lane,
                                     f32x4& acc00, f32x4& acc01, f32x4& acc10, f32x4& acc11)
{
    f32x4 bx0[8], bx1[8], by0[8], by1[8];
    asm volatile("s_waitcnt vmcnt(0)" ::: "memory");   // exact-count precondition
    ISSUE_CHUNK(bx0, bx1, p0, p1);
    ISSUE_CHUNK(by0, by1, p0 + 256, p1 + 256);
    WAITV(16, bx0, bx1);
    MFMA8(abase + 0, bx0, bx1);
    ISSUE_CHUNK(bx0, bx1, p0 + 512, p1 + 512);
    WAITV(16, by0, by1);
    MFMA8(abase + 8, by0, by1);
    ISSUE_CHUNK(by0, by1, p0 + 768, p1 + 768);
    WAITV(16, bx0, bx1);
    MFMA8(abase + 16, bx0, bx1);
    WAITV(0, by0, by1);
    MFMA8(abase + 24, by0, by1);
}

__device__ __forceinline__ void epilogue(SMem& sm, f32x4 acc00, f32x4 acc01, f32x4 acc10, f32x4 acc11,
                                         float creg[4], bf16* hdst, int hu0, bool extra_tanh) {
    const int tid = threadIdx.x;
    const int lane = tid & 63, wv = tid >> 6, quad = lane >> 4, l15 = lane & 15;
    const int colb = (wv & 3) * 32;
    #pragma unroll
    for (int ph = 0; ph < 2; ++ph) {
        if ((wv >> 2) == ph) {
            #pragma unroll
            for (int r = 0; r < 4; ++r) {
                sm.scratch[(quad * 4 + r) * 129 + colb + l15]           = acc00[r];
                sm.scratch[(quad * 4 + r) * 129 + colb + 16 + l15]      = acc01[r];
                sm.scratch[(16 + quad * 4 + r) * 129 + colb + l15]      = acc10[r];
                sm.scratch[(16 + quad * 4 + r) * 129 + colb + 16 + l15] = acc11[r];
            }
        }
        __syncthreads();
        #pragma unroll
        for (int pi = 0; pi < 2; ++pi) {
            int idx = pi * NTHR + tid;
            int bl = idx & 127, hu = idx >> 7;
            float gi = sm.scratch[hu * 129 + bl]        + sm.bias[hu];
            float gf = sm.scratch[(8 + hu) * 129 + bl]  + sm.bias[8 + hu];
            float gg = sm.scratch[(16 + hu) * 129 + bl] + sm.bias[16 + hu];
            float go = sm.scratch[(24 + hu) * 129 + bl] + sm.bias[24 + hu];
            float iv = fsig(gi), fv = fsig(gf), gv = ftanh(gg), ov = fsig(go);
            float c = fv * creg[ph * 2 + pi] + iv * gv;
            creg[ph * 2 + pi] = c;
            float h = ov * ftanh(c);
            if (extra_tanh) h = ftanh(h);
            sm.hstage[hu * 256 + (bl + 128 * ph)] = (bf16)h;
        }
        __syncthreads();
    }
    if (tid < 256) {
        bf16x8 v;
        #pragma unroll
        for (int e = 0; e < 8; ++e) v[e] = sm.hstage[e * 256 + tid];
        bf16* p = hdst + (size_t)tid * Hh + hu0;
        f32x4 pv = __builtin_bit_cast(f32x4, v);
        STX4_SC1(p, pv);                    // publish through MALL for next stage's copy-in
    }
}

__global__ void __launch_bounds__(NTHR, 2)
lstm_kernel(const float* __restrict__ y,
            const float* __restrict__ Wih1, const float* __restrict__ Whh1,
            const float* __restrict__ bih1, const float* __restrict__ bhh1,
            const float* __restrict__ Wih2, const float* __restrict__ Whh2,
            const float* __restrict__ bih2, const float* __restrict__ bhh2,
            const float* __restrict__ Wout, const float* __restrict__ bout,
            float* __restrict__ out,
            bf16* __restrict__ h1b0, bf16* __restrict__ h1b1,
            bf16* __restrict__ h2b0, bf16* __restrict__ h2b1,
            char* __restrict__ ctl, bf16* __restrict__ stg)
{
    __shared__ SMem sm;
    __shared__ int sh_rank, sh_total;
    const int tid = threadIdx.x;
    const int bid = blockIdx.x;
    const bool isL2 = bid >= 128;
    const int hu0 = (bid & 127) * 8;
    const int KI = isL2 ? 64 : 40;
    const int lane = tid & 63;
    const int wv = tid >> 6;
    const int quad = lane >> 4;
    const int l15 = lane & 15;

    unsigned* boot   = (unsigned*)ctl;                  // 256 u32
    unsigned* regcnt = (unsigned*)(ctl + 1024);         // 8 u32
    unsigned* arrive = (unsigned*)(ctl + 2048);         // 256 u32 (global epochs)
    unsigned* xcpyB  = (unsigned*)(ctl + 4096);         // 8 XCD x 256 u32 (local epochs)

    int xcc;
    asm("s_getreg_b32 %0, hwreg(HW_REG_XCC_ID)" : "=s"(xcc));
    xcc &= 7;
    if (tid == 0)
        sh_rank = (int)__hip_atomic_fetch_add(&regcnt[xcc], 1u, __ATOMIC_RELAXED,
                                              __HIP_MEMORY_SCOPE_AGENT);
    unsigned* xcpy = xcpyB + xcc * 256;
    // staging: per XCD 2 parities x (st1 512KB + st2 512KB) = 2 MB
    bf16* stgx = stg + (size_t)xcc * (4 * Bb * Hh);

    // ---- one-time: bias + weights into LDS (MFMA A-frag order) ----
    if (tid < 32) {
        int gate = tid >> 3, j = tid & 7;
        int grow = gate * Hh + hu0 + j;
        sm.bias[tid] = isL2 ? (bih2[grow] + bhh2[grow]) : (bih1[grow] + bhh1[grow]);
    }
    for (int slot = tid; slot < 2 * KI * 64; slot += NTHR) {
        int mt = slot / (KI * 64);
        int ki = (slot / 64) % KI;
        int ln = slot & 63;
        int row = mt * 16 + (ln & 15);
        int k = ki * 32 + (ln >> 4) * 8;
        int gate = row >> 3, j = row & 7;
        int grow = gate * Hh + hu0 + j;
        const float* src;
        if (!isL2) src = (k < Ff) ? (Wih1 + (size_t)grow * Ff + k) : (Whh1 + (size_t)grow * Hh + (k - Ff));
        else       src = (k < Hh) ? (Wih2 + (size_t)grow * Hh + k) : (Whh2 + (size_t)grow * Hh + (k - Hh));
        bf16x8 fr;
        #pragma unroll
        for (int e = 0; e < 8; ++e) fr[e] = (bf16)src[e];
        sm.w[slot] = fr;
    }
    float creg[4] = {0.f, 0.f, 0.f, 0.f};
    __syncthreads();

    // bootstrap grid barrier (agent-scope flags — R2/R3-proven)
    if (tid == 0)
        __hip_atomic_store(&boot[bid], 1u, __ATOMIC_RELAXED, __HIP_MEMORY_SCOPE_AGENT);
    if (tid < 64) {
        for (;;) {
            int ok = 1;
            #pragma unroll
            for (int j = 0; j < 4; ++j)
                ok &= (__hip_atomic_load(&boot[tid * 4 + j], __ATOMIC_RELAXED,
                                         __HIP_MEMORY_SCOPE_AGENT) >= 1u);
            if (__all(ok)) break;
            __builtin_amdgcn_s_sleep(4);
        }
    }
    __syncthreads();
    if (tid == 0)
        sh_total = (int)__hip_atomic_load(&regcnt[xcc], __ATOMIC_RELAXED, __HIP_MEMORY_SCOPE_AGENT);
    __syncthreads();
    const int rank = sh_rank, total = sh_total;

    const int nb0 = wv * 32 + l15;
    const bf16x8* wA0 = sm.w;
    const bf16x8* wA1 = sm.w + KI * 64;

    for (int s = 0; s <= Tt; ++s) {
        const int t = isL2 ? (s - 1) : s;
        const bool active = isL2 ? (s >= 1) : (s < Tt);
        const int par = s & 1;
        bf16* st1 = stgx + (size_t)par * (2 * Bb * Hh);
        bf16* st2 = st1 + Bb * Hh;
        f32x4 acc00 = {0,0,0,0}, acc01 = {0,0,0,0}, acc10 = {0,0,0,0}, acc11 = {0,0,0,0};

        // ---- barrier-independent x-part for L1 blocks (overlaps barrier skew) ----
        if (!isL2 && active) {
            const f32x4* x0v = (const f32x4*)(y + ((size_t)nb0 * Tt + t) * Ff) + quad * 2;
            const f32x4* x1v = x0v + (size_t)16 * Tt * (Ff / 4);
            #pragma unroll
            for (int ki = 0; ki < 8; ++ki) {
                bf16x8 a0 = wA0[ki * 64 + lane];
                bf16x8 a1 = wA1[ki * 64 + lane];
                f32x4 u0 = x0v[ki * 8], u1 = x0v[ki * 8 + 1];
                f32x4 w0 = x1v[ki * 8], w1 = x1v[ki * 8 + 1];
                bf16x8 b0, b1;
                #pragma unroll
                for (int e = 0; e < 4; ++e) {
                    b0[e] = (bf16)u0[e]; b0[4 + e] = (bf16)u1[e];
                    b1[e] = (bf16)w0[e]; b1[4 + e] = (bf16)w1[e];
                }
                acc00 = MFMA(a0, b0, acc00); acc10 = MFMA(a1, b0, acc10);
                acc01 = MFMA(a0, b1, acc01); acc11 = MFMA(a1, b1, acc11);
            }
        }

        if (s >= 1) {
            const unsigned e = (unsigned)s;
            // ---- global release wait: all blocks arrived epoch s ----
            if (tid < 64) {
                for (;;) {
                    int ok = 1;
                    #pragma unroll
                    for (int j = 0; j < 4; ++j)
                        ok &= (__hip_atomic_load(&arrive[tid * 4 + j], __ATOMIC_RELAXED,
                                                 __HIP_MEMORY_SCOPE_AGENT) >= e);
                    if (__all(ok)) break;
                    __builtin_amdgcn_s_sleep(2);
                }
            }
            __syncthreads();

            // ---- XCD-local copy-in: h1[s-1] (+ h2[s-2]) into parity staging ----
            const int gtid = rank * NTHR + tid;
            const int stride = total * NTHR;
            const int nvec = (Bb * Hh * 2) / 16;    // 32768 f32x4
            {
                const f32x4* src = (const f32x4*)(((s - 1) & 1) ? h1b1 : h1b0);
                f32x4* dst = (f32x4*)st1;
                for (int c = gtid; c < nvec; c += 2 * stride) {
                    int c1 = c + stride;
                    f32x4 v0, v1;
                    LDX4_SC1(v0, src + c);
                    if (c1 < nvec) LDX4_SC1(v1, src + c1);
                    asm volatile("s_waitcnt vmcnt(0)" ::: "memory");
                    dst[c] = v0;                    // plain store -> dirty in local L2
                    if (c1 < nvec) dst[c1] = v1;
                }
            }
            if (s >= 2) {
                const f32x4* src = (const f32x4*)(((s - 2) & 1) ? h2b1 : h2b0);
                f32x4* dst = (f32x4*)st2;
                for (int c = gtid; c < nvec; c += 2 * stride) {
                    int c1 = c + stride;
                    f32x4 v0, v1;
                    LDX4_SC1(v0, src + c);
                    if (c1 < nvec) LDX4_SC1(v1, src + c1);
                    asm volatile("s_waitcnt vmcnt(0)" ::: "memory");
                    dst[c] = v0;
                    if (c1 < nvec) dst[c1] = v1;
                }
            }
            L1_INV();   // flash-invalidate vector L1 so plain staging reads can't hit stale lines

            // ---- local copy-barrier (agent-scope flags, R3-proven pattern) ----
            __syncthreads();                        // drain this block's staging stores
            if (tid == 0)
                __hip_atomic_store(&xcpy[rank], e, __ATOMIC_RELAXED, __HIP_MEMORY_SCOPE_AGENT);
            if (tid < 64) {
                for (;;) {
                    int ok = 1;
                    for (int j = tid; j < 256; j += 64) {
                        if (j < total)
                            ok &= (__hip_atomic_load(&xcpy[j], __ATOMIC_RELAXED,
                                                     __HIP_MEMORY_SCOPE_AGENT) >= e);
                    }
                    if (__all(ok)) break;
                    __builtin_amdgcn_s_sleep(1);
                }
            }
            __syncthreads();
        }

        // ---- h-parts (cached reads of XCD-local staging) + epilogue ----
        if (active) {
            if (!isL2) {
                if (t > 0) {
                    const bf16* p0 = st1 + (size_t)nb0 * Hh + quad * 8;
                    mm32(wA0, wA1, 8, p0, p0 + 16 * Hh, lane, acc00, acc01, acc10, acc11);
                }
                epilogue(sm, acc00, acc01, acc10, acc11, creg, (t & 1) ? h1b1 : h1b0, hu0, false);
            } else {
                const bf16* p0 = st1 + (size_t)nb0 * Hh + quad * 8;
                mm32(wA0, wA1, 0, p0, p0 + 16 * Hh, lane, acc00, acc01, acc10, acc11);
                if (t > 0) {
                    const bf16* q0 = st2 + (size_t)nb0 * Hh + quad * 8;
                    mm32(wA0, wA1, 32, q0, q0 + 16 * Hh, lane, acc00, acc01, acc10, acc11);
                }
                epilogue(sm, acc00, acc01, acc10, acc11, creg, (t & 1) ? h2b1 : h2b0, hu0, true);
            }
        }

        // ---- arrive epoch s+1 (non-blocking) ----
        __syncthreads();                    // drains all waves' vmem incl. sc1 publishes
        if (tid == 0)
            __hip_atomic_store(&arrive[bid], (unsigned)(s + 1), __ATOMIC_RELAXED,
                               __HIP_MEMORY_SCOPE_AGENT);
    }

    // final wait: all arrived Tt+1 -> h2[511] globally visible
    {
        const unsigned e = (unsigned)(Tt + 1);
        if (tid < 64) {
            for (;;) {
                int ok = 1;
                #pragma unroll
                for (int j = 0; j < 4; ++j)
                    ok &= (__hip_atomic_load(&arrive[tid * 4 + j], __ATOMIC_RELAXED,
                                             __HIP_MEMORY_SCOPE_AGENT) >= e);
                if (__all(ok)) break;
                __builtin_amdgcn_s_sleep(2);
            }
        }
        __syncthreads();
    }

    // ---- out = relu(h2[511] @ Wout^T + bout); h2[511] in h2b1 (MALL reads) ----
    if (bid < 16) {
        const int bb = bid * 16 + l15;
        const float* ap = Wout + (size_t)(wv * 16 + l15) * Hh + quad * 8;
        const bf16* bp = h2b1 + (size_t)bb * Hh + quad * 8;
        f32x4 acc = {0,0,0,0};
        for (int ki = 0; ki < 32; ++ki) {
            bf16x8 a;
            #pragma unroll
            for (int e = 0; e < 8; ++e) a[e] = (bf16)ap[ki * 32 + e];
            f32x4 braw;
            LDX4_SC1(braw, (const f32x4*)(bp + ki * 32));
            asm volatile("s_waitcnt vmcnt(0)" ::: "memory");
            bf16x8 b = __builtin_bit_cast(bf16x8, braw);
            acc = MFMA(a, b, acc);
        }
        #pragma unroll
        for (int r = 0; r < 4; ++r) {
            int orow = wv * 16 + quad * 4 + r;
            float v = acc[r] + bout[orow];
            out[(size_t)bb * Cc + orow] = fmaxf(v, 0.f);
        }
    }
}

extern "C" void kernel_launch(void* const* d_in, const int* in_sizes, int n_in,
                              void* d_out, int out_size, void* d_ws, size_t ws_size,
                              hipStream_t stream) {
    const float* y    = (const float*)d_in[0];
    const float* Wih1 = (const float*)d_in[1];
    const float* Whh1 = (const float*)d_in[2];
    const float* bih1 = (const float*)d_in[3];
    const float* bhh1 = (const float*)d_in[4];
    const float* Wih2 = (const float*)d_in[5];
    const float* Whh2 = (const float*)d_in[6];
    const float* bih2 = (const float*)d_in[7];
    const float* bhh2 = (const float*)d_in[8];
    const float* Wout = (const float*)d_in[9];
    const float* bout = (const float*)d_in[10];
    float* out = (float*)d_out;

    char* ws = (char*)d_ws;
    char* ctl = ws;                                  // 32 KB control region
    bf16* h1b0 = (bf16*)(ws + 32768);
    bf16* h1b1 = (bf16*)(ws + 32768 + 1 * 524288);
    bf16* h2b0 = (bf16*)(ws + 32768 + 2 * 524288);
    bf16* h2b1 = (bf16*)(ws + 32768 + 3 * 524288);
    bf16* stg  = (bf16*)(ws + 32768 + 4 * 524288);   // 8 XCDs x 2 MB parity staging = 16 MB

    hipMemsetAsync(ctl, 0, 32768, stream);

    void* args[] = { &y, &Wih1, &Whh1, &bih1, &bhh1, &Wih2, &Whh2, &bih2, &bhh2,
                     &Wout, &bout, &out, &h1b0, &h1b1, &h2b0, &h2b1, &ctl, &stg };
    hipLaunchCooperativeKernel((void*)lstm_kernel, dim3(NBLK), dim3(NTHR), args, 0, stream);
}